// Round 13
// baseline (793.702 us; speedup 1.0000x reference)
//
#include <hip/hip_runtime.h>
#include <hip/hip_bf16.h>

typedef unsigned short u16;
typedef unsigned int u32;
typedef __attribute__((ext_vector_type(4))) float f32x4;
typedef __attribute__((ext_vector_type(8))) short short8;
typedef __attribute__((ext_vector_type(8))) __bf16 bf16x8;

#define TBN ((size_t)65536)  // T*B

// frag-layout offsets in u16 elements inside d_ws
#define OFF_WIH  0         // [3 g][13 ct][7 ks][512]; gate stride 46592
#define OFF_WHH  139776
#define OFF_WP1  279552    // [13][7][512]
#define OFF_WQ1D 326144
#define OFF_WP2  372736    // [4][7][512]
#define OFF_WQ2  387072    // PAIRED packing: tile ct, fc<8 -> qm col ct*8+fc; fc>=8 -> qs col ct*8+fc-8
#define OFF_WQ1E 401408    // [32 ks][13 ct][512]
#define OFF_WRIF 614400    // [13 ct][2 ks][512]
#define FRAG_TOTAL 627712  // = 512*1226
#define GSTR 46592

__device__ __forceinline__ u16 f2bf(float f) {
  unsigned u = __builtin_bit_cast(unsigned, f);
  unsigned r = u + 0x7fffu + ((u >> 16) & 1u);
  return (u16)(r >> 16);
}
__device__ __forceinline__ float bf2f(u16 v) {
  unsigned u = ((unsigned)v) << 16;
  return __builtin_bit_cast(float, u);
}
__device__ __forceinline__ float fsig(float x) {
  return __builtin_amdgcn_rcpf(1.f + __expf(-x));
}
__device__ __forceinline__ float ftanh(float x) {
  return 1.f - 2.f * __builtin_amdgcn_rcpf(__expf(2.f * x) + 1.f);
}
__device__ __forceinline__ float fsoftplus(float x) {
  return (x > 20.f) ? x : __logf(1.f + __expf(x));
}
__device__ __forceinline__ float felu(float x) {
  return (x > 0.f) ? x : (__expf(x) - 1.f);
}
__device__ __forceinline__ f32x4 mfma16(short8 a, short8 b, f32x4 c) {
  return __builtin_amdgcn_mfma_f32_16x16x32_bf16(
      __builtin_bit_cast(bf16x8, a), __builtin_bit_cast(bf16x8, b), c, 0, 0, 0);
}
// barrier that does NOT drain vmcnt: LDS-safe, lets global loads/stores fly
__device__ __forceinline__ void softbar() {
  asm volatile("s_waitcnt lgkmcnt(0)\n\ts_barrier" ::: "memory");
}

// ---------------- P0: pack weights into MFMA B-fragment order (bf16) --------
__global__ __launch_bounds__(512) void prep_frags(
    const float* __restrict__ Wih, const float* __restrict__ Whh,
    const float* __restrict__ Wp1, const float* __restrict__ Wq1,
    const float* __restrict__ Wp2, const float* __restrict__ Wq2,
    const float* __restrict__ Wri, u16* __restrict__ ws) {
  int id = blockIdx.x * 512 + threadIdx.x;
  float v = 0.f;
  if (id < 279552) {                       // WIH / WHH  (K=200, N=3x200)
    const float* W = (id < 139776) ? Wih : Whh;
    int idx2 = (id < 139776) ? id : id - 139776;
    int fb = idx2 >> 9, r = idx2 & 511, l = r >> 3, i = r & 7;
    int g = fb / 91, rem = fb % 91, ct = rem / 7, ks = rem % 7;
    int k = ks*32 + ((l >> 4) << 3) + i;
    int col = ct*16 + (l & 15);
    if (k < 200 && col < 200) v = W[k*600 + g*200 + col];
  } else if (id < 372736) {                // WP1 / WQ1D  (K=200, N=200)
    const float* W = (id < 326144) ? Wp1 : Wq1;
    int idx2 = (id < 326144) ? id - 279552 : id - 326144;
    int fb = idx2 >> 9, r = idx2 & 511, l = r >> 3, i = r & 7;
    int ct = fb / 7, ks = fb % 7;
    int k = ks*32 + ((l >> 4) << 3) + i;
    int col = ct*16 + (l & 15);
    if (k < 200 && col < 200) v = W[k*200 + col];
  } else if (id < 387072) {                // WP2  (K=200, N=60)
    int idx2 = id - 372736;
    int fb = idx2 >> 9, r = idx2 & 511, l = r >> 3, i = r & 7;
    int ct = fb / 7, ks = fb % 7;
    int k = ks*32 + ((l >> 4) << 3) + i;
    int col = ct*16 + (l & 15);
    if (k < 200 && col < 60) v = Wp2[k*60 + col];
  } else if (id < 401408) {                // WQ2 (PAIRED qm/qs packing)
    int idx2 = id - 387072;
    int fb = idx2 >> 9, r = idx2 & 511, l = r >> 3, i = r & 7;
    int ct = fb / 7, ks = fb % 7;
    int k = ks*32 + ((l >> 4) << 3) + i;
    int fc = l & 15;
    int qcol = ct*8 + (fc & 7);
    int col = (fc < 8) ? qcol : (30 + qcol);   // fc<8: qm col; fc>=8: qs col
    if (k < 200 && qcol < 30) v = Wq2[k*60 + col];
  } else if (id < 614400) {                // WQ1E (emb rows of Wq1, K=1024)
    int idx2 = id - 401408;
    int fb = idx2 >> 9, r = idx2 & 511, l = r >> 3, i = r & 7;
    int ks = fb / 13, ct = fb % 13;
    int k = ks*32 + ((l >> 4) << 3) + i;
    int col = ct*16 + (l & 15);
    if (col < 200) v = Wq1[(size_t)(200 + k)*200 + col];
  } else {                                 // WRIF (K=36 pad 64, N=200)
    int idx2 = id - 614400;
    int fb = idx2 >> 9, r = idx2 & 511, l = r >> 3, i = r & 7;
    int ct = fb >> 1, ks = fb & 1;
    int k = ks*32 + ((l >> 4) << 3) + i;
    int col = ct*16 + (l & 15);
    if (k < 36 && col < 200) v = Wri[k*200 + col];
  }
  ws[id] = f2bf(v);
}

// ---------------- P1: embq (bf16) = obs_embed @ Wq1[200:,:] + bq1 -----------
__global__ __launch_bounds__(512) void embq_kernel(
    const float* __restrict__ obs, const float* __restrict__ bq1,
    const u16* __restrict__ ws, u16* __restrict__ embq) {
  __shared__ __align__(16) u16 Bl[6656];   // 13 frag-blocks x 1KB
  const int tid = threadIdx.x;
  const int w = tid >> 6, l = tid & 63;
  const int lr = l & 15, lk = (l >> 4) << 3, crw = (l >> 4) << 2;
  const size_t mb = (size_t)blockIdx.x * 128;
  const float* ap = obs + (mb + (size_t)w*16 + lr) * 1024 + lk;
  const u16* wsrc = ws + OFF_WQ1E;
  f32x4 zero = {0.f, 0.f, 0.f, 0.f};
  f32x4 acc[13];
  #pragma unroll
  for (int c = 0; c < 13; ++c) acc[c] = zero;
  for (int ks = 0; ks < 32; ++ks) {
    f32x4 a0 = __builtin_nontemporal_load((const f32x4*)(ap));
    f32x4 a1 = __builtin_nontemporal_load((const f32x4*)(ap + 4));
    ap += 32;
    __syncthreads();
    {
      const u16* src = wsrc + (size_t)ks * 6656;
      *(short8*)(Bl + tid*8) = *(const short8*)(src + tid*8);
      int idx = 512 + tid;
      if (idx < 832)
        *(short8*)(Bl + idx*8) = *(const short8*)(src + idx*8);
    }
    __syncthreads();
    short8 af;
    af[0]=(short)f2bf(a0[0]); af[1]=(short)f2bf(a0[1]); af[2]=(short)f2bf(a0[2]); af[3]=(short)f2bf(a0[3]);
    af[4]=(short)f2bf(a1[0]); af[5]=(short)f2bf(a1[1]); af[6]=(short)f2bf(a1[2]); af[7]=(short)f2bf(a1[3]);
    #pragma unroll
    for (int c = 0; c < 13; ++c) {
      short8 bf = *(const short8*)(Bl + c*512 + l*8);
      acc[c] = mfma16(af, bf, acc[c]);
    }
  }
  #pragma unroll
  for (int c = 0; c < 13; ++c) {
    int col = c*16 + lr;
    if (col < 200) {
      float bias = bq1[col];
      #pragma unroll
      for (int i = 0; i < 4; ++i) {
        size_t row = mb + (size_t)w*16 + crw + i;
        __builtin_nontemporal_store(f2bf(acc[c][i] + bias), &embq[row*400 + col]);
      }
    }
  }
}

// ---------------- R: the 64-step rollout, 64 blocks x 16 batch rows ---------
__global__ __launch_bounds__(512, 1) void rollout_kernel(
    const float* __restrict__ action, const float* __restrict__ prev_stoch,
    const float* __restrict__ prev_deter, const float* __restrict__ noise_post,
    const float* __restrict__ bri, const float* __restrict__ bih,
    const float* __restrict__ bhh, const float* __restrict__ bq2,
    const u16* __restrict__ ws, float* __restrict__ out) {
  float* o_d1  = out + TBN*90;
  float* o_qm  = out + TBN*290;
  float* o_qs  = out + TBN*320;
  float* o_qst = out + TBN*350;
  float* o_d2  = out + TBN*380;          // rows hold embq(t) bf16 until consumed
  const u32* embq32 = (const u32*)o_d2;

  __shared__ __align__(16) u16 s_wqd[46592];          // Wq1d frags, LDS-resident
  __shared__ float s_bih[600], s_bhh[600], s_bri[200], s_bq2[60];
  __shared__ float s_deter[16][200];
  __shared__ __align__(16) u16 s_dbf2[2][16][232];
  __shared__ __align__(16) u16 s_abf[16][64];
  __shared__ __align__(16) u16 s_xbf[16][232];
  __shared__ __align__(16) u16 s_h2[16][232];
  __shared__ __align__(4)  u16 s_embq[3200];          // single buffer
  __shared__ float s_noise[2][480];

  const int tid = threadIdx.x;
  const int w = tid >> 6, l = tid & 63;
  const int lr = l & 15, lk = (l >> 4) << 3, crw = (l >> 4) << 2;
  const int rb = blockIdx.x * 16;
  const f32x4 fzero = {0.f, 0.f, 0.f, 0.f};
  const int uA0 = w;
  const int uA1 = (w < 5) ? (8 + w) : 12;
  const bool validR1 = (w < 5);
  const int lt = tid - 256;                // 0..255 for waves 4-7

  // ---- zero-init ----
  for (int idx = tid; idx < 16*232; idx += 512) {
    (&s_xbf[0][0])[idx] = 0; (&s_h2[0][0])[idx] = 0;
    (&s_dbf2[0][0][0])[idx] = 0; (&s_dbf2[1][0][0])[idx] = 0;
  }
  for (int idx = tid; idx < 16*64; idx += 512) (&s_abf[0][0])[idx] = 0;
  __syncthreads();

  for (int idx = tid; idx < 600; idx += 512) { s_bih[idx] = bih[idx]; s_bhh[idx] = bhh[idx]; }
  if (tid < 200) s_bri[tid] = bri[tid];
  if (tid < 60)  s_bq2[tid] = bq2[tid];
  // Wq1d -> LDS (once)
  for (int i = tid; i < 5824; i += 512)
    ((short8*)s_wqd)[i] = ((const short8*)(ws + OFF_WQ1D))[i];
  for (int idx = tid; idx < 3200; idx += 512) {
    int r = idx/200, c = idx - r*200;
    float d = prev_deter[(rb + r)*200 + c];
    s_deter[r][c] = d;
    s_dbf2[0][r][c] = f2bf(d);
  }
  if (tid < 480) { int r = tid/30, c = tid - r*30;
    s_abf[r][6 + c] = f2bf(prev_stoch[(rb + r)*30 + c]); }
  if (tid < 96) { s_abf[tid/6][tid - (tid/6)*6] = f2bf(action[(size_t)rb*6 + tid]); }
  {
    const u32* esrc = embq32 + (size_t)rb * 200;
    u32* ed = (u32*)s_embq;
    #pragma unroll
    for (int q = 0; q < 4; ++q) {
      int idx = q*512 + tid;
      if (idx < 1600) { int r = idx/100, c = idx - r*100; ed[idx] = esrc[r*200 + c]; }
    }
  }
  if (tid < 480) s_noise[0][tid] = noise_post[(size_t)rb*30 + tid];

  // resident fragments
  short8 wri0[2], wri1[2], wq2f[7];
  #pragma unroll
  for (int ks = 0; ks < 2; ++ks) {
    wri0[ks] = *(const short8*)(ws + OFF_WRIF + ((uA0*2 + ks) << 9) + l*8);
    wri1[ks] = *(const short8*)(ws + OFF_WRIF + ((uA1*2 + ks) << 9) + l*8);
  }
  #pragma unroll
  for (int ks = 0; ks < 7; ++ks)
    wq2f[ks] = *(const short8*)(ws + OFF_WQ2 + (((w & 3)*7 + ks) << 9) + l*8);
  __syncthreads();

  for (int t = 0; t < 64; ++t) {
    const size_t brow = (size_t)t*1024 + rb;
    const int sc = t & 1, sn = sc ^ 1;   // parity for noise AND s_dbf2

    // ---- A': x = elu([act|stoch]@Wri + bri) via MFMA ----
    {
      short8 a0 = *(const short8*)&s_abf[lr][lk];
      short8 a1 = *(const short8*)&s_abf[lr][32 + lk];
      f32x4 acc = mfma16(a1, wri0[1], mfma16(a0, wri0[0], fzero));
      int col = uA0*16 + lr;                    // < 128
      #pragma unroll
      for (int i = 0; i < 4; ++i)
        s_xbf[crw + i][col] = f2bf(felu(acc[i] + s_bri[col]));
      if (validR1) {
        f32x4 acc2 = mfma16(a1, wri1[1], mfma16(a0, wri1[0], fzero));
        int col2 = uA1*16 + lr;
        if (col2 < 200) {
          #pragma unroll
          for (int i = 0; i < 4; ++i)
            s_xbf[crw + i][col2] = f2bf(felu(acc2[i] + s_bri[col2]));
        }
      }
    }
    softbar();

    // ---- B'+C: gates GEMM (all 3 gates per unit) + in-register GRU combine ----
    #pragma unroll
    for (int jr = 0; jr < 2; ++jr) {
      const int u = jr ? uA1 : uA0;
      const bool valid = jr ? validR1 : true;
      if (valid) {
        const u32 base = (u32)(((u*7) << 9) + l*8);
        short8 g0i[7], g0h[7], g1i[7], g1h[7], g2i[7], g2h[7];
        #pragma unroll
        for (int ks = 0; ks < 7; ++ks) {
          g0i[ks] = *(const short8*)(ws + OFF_WIH + base + ks*512);
          g0h[ks] = *(const short8*)(ws + OFF_WHH + base + ks*512);
        }
        #pragma unroll
        for (int ks = 0; ks < 7; ++ks) {
          g1i[ks] = *(const short8*)(ws + OFF_WIH + GSTR + base + ks*512);
          g1h[ks] = *(const short8*)(ws + OFF_WHH + GSTR + base + ks*512);
        }
        f32x4 aR = fzero;
        #pragma unroll
        for (int ks = 0; ks < 7; ++ks) {
          short8 ax = *(const short8*)&s_xbf[lr][ks*32 + lk];
          short8 ad = *(const short8*)&s_dbf2[sc][lr][ks*32 + lk];
          aR = mfma16(ad, g0h[ks], mfma16(ax, g0i[ks], aR));
        }
        #pragma unroll
        for (int ks = 0; ks < 7; ++ks) {
          g2i[ks] = *(const short8*)(ws + OFF_WIH + 2*GSTR + base + ks*512);
          g2h[ks] = *(const short8*)(ws + OFF_WHH + 2*GSTR + base + ks*512);
        }
        f32x4 aZ = fzero;
        #pragma unroll
        for (int ks = 0; ks < 7; ++ks) {
          short8 ax = *(const short8*)&s_xbf[lr][ks*32 + lk];
          short8 ad = *(const short8*)&s_dbf2[sc][lr][ks*32 + lk];
          aZ = mfma16(ad, g1h[ks], mfma16(ax, g1i[ks], aZ));
        }
        f32x4 aN = fzero, aH = fzero;
        #pragma unroll
        for (int ks = 0; ks < 7; ++ks) {
          short8 ax = *(const short8*)&s_xbf[lr][ks*32 + lk];
          short8 ad = *(const short8*)&s_dbf2[sc][lr][ks*32 + lk];
          aN = mfma16(ax, g2i[ks], aN);
          aH = mfma16(ad, g2h[ks], aH);
        }
        int col = u*16 + lr;
        if (col < 200) {
          float bR = s_bih[col]       + s_bhh[col];
          float bZ = s_bih[200 + col] + s_bhh[200 + col];
          float bN = s_bih[400 + col];
          float bH = s_bhh[400 + col];
          #pragma unroll
          for (int i = 0; i < 4; ++i) {
            int row = crw + i;
            float rg = fsig(aR[i] + bR);
            float zg = fsig(aZ[i] + bZ);
            float ng = ftanh(aN[i] + bN + rg*(aH[i] + bH));
            float dn = (1.f - zg)*ng + zg*s_deter[row][col];
            s_deter[row][col] = dn;
            s_dbf2[sn][row][col] = f2bf(dn);
          }
        }
      }
    }
    // stream prefetch for t+1 — waves 4-7 only (issued AFTER their frag loads)
    u32 pe[7]; float pact = 0.f, pn0 = 0.f, pn1 = 0.f;
    if (w >= 4) {
      const int t2 = (t < 63) ? (t + 1) : 63;
      const size_t brow2 = (size_t)t2*1024 + rb;
      const u32* esrc = embq32 + brow2*200;
      #pragma unroll
      for (int q = 0; q < 7; ++q) {
        int idx = q*256 + lt;
        if (idx < 1600) { int r = idx/100, c = idx - r*100; pe[q] = esrc[r*200 + c]; }
      }
      if (lt < 96)  pact = action[brow2*6 + lt];
      { int idx = lt;       if (idx < 480) pn0 = noise_post[brow2*30 + idx]; }
      { int idx = 256 + lt; if (idx < 480) pn1 = noise_post[brow2*30 + idx]; }
    }
    softbar();   // deter ready; streams in flight

    // ---- D: h2 = elu(deter_new@Wq1d + embq), Wq1d from LDS ----
    {
      f32x4 acc = fzero;
      #pragma unroll
      for (int ks = 0; ks < 7; ++ks) {
        short8 ad = *(const short8*)&s_dbf2[sn][lr][ks*32 + lk];
        short8 bw = *(const short8*)&s_wqd[((uA0*7 + ks) << 9) + l*8];
        acc = mfma16(ad, bw, acc);
      }
      {
        int col = uA0*16 + lr;                  // < 128
        #pragma unroll
        for (int i = 0; i < 4; ++i) {
          int row = crw + i;
          float v = acc[i] + bf2f(s_embq[row*200 + col]);
          s_h2[row][col] = f2bf(felu(v));
        }
      }
      if (validR1) {
        f32x4 acc2 = fzero;
        #pragma unroll
        for (int ks = 0; ks < 7; ++ks) {
          short8 ad = *(const short8*)&s_dbf2[sn][lr][ks*32 + lk];
          short8 bw = *(const short8*)&s_wqd[((uA1*7 + ks) << 9) + l*8];
          acc2 = mfma16(ad, bw, acc2);
        }
        int col2 = uA1*16 + lr;
        if (col2 < 200) {
          #pragma unroll
          for (int i = 0; i < 4; ++i) {
            int row = crw + i;
            float v = acc2[i] + bf2f(s_embq[row*200 + col2]);
            s_h2[row][col2] = f2bf(felu(v));
          }
        }
      }
    }
    softbar();   // h2 ready; embq consumed

    // ---- E (merged): head+sample (waves 0-3, paired cols + shfl);
    //      d-stores + t+1 staging (waves 4-7) ----
    if (w < 4) {
      f32x4 acc = fzero;
      #pragma unroll
      for (int ks = 0; ks < 7; ++ks) {
        short8 a = *(const short8*)&s_h2[lr][ks*32 + lk];
        acc = mfma16(a, wq2f[ks], acc);
      }
      const int qcol = w*8 + (lr & 7);
      const bool isQm = (lr < 8);
      const float bias = isQm ? s_bq2[qcol] : s_bq2[30 + qcol];
      #pragma unroll
      for (int i = 0; i < 4; ++i) {
        int row = crw + i;
        float v = acc[i] + bias;
        float s = fsoftplus(v) + 0.1f;          // meaningful on qs lanes
        float sv = __shfl(s, l | 8, 64);        // qm lane pulls its qs partner
        if (qcol < 30) {
          size_t go = (brow + row)*30 + qcol;
          if (isQm) {
            __builtin_nontemporal_store(v, &o_qm[go]);
            float qst = v + sv * s_noise[sc][row*30 + qcol];
            __builtin_nontemporal_store(qst, &o_qst[go]);
            s_abf[row][6 + qcol] = f2bf(qst);
          } else {
            __builtin_nontemporal_store(s, &o_qs[go]);
          }
        }
      }
    } else {
      for (int idx = lt; idx < 3200; idx += 256) {
        int r = idx/200, j = idx - r*200;
        float dv = s_deter[r][j];
        __builtin_nontemporal_store(dv, &o_d1[(brow + r)*200 + j]);
        __builtin_nontemporal_store(dv, &o_d2[(brow + r)*200 + j]);
      }
      u32* ed = (u32*)s_embq;
      #pragma unroll
      for (int q = 0; q < 7; ++q) {
        int idx = q*256 + lt;
        if (idx < 1600) ed[idx] = pe[q];
      }
      if (lt < 96) s_abf[lt/6][lt - (lt/6)*6] = f2bf(pact);
      { int idx = lt;       if (idx < 480) s_noise[sn][idx] = pn0; }
      { int idx = 256 + lt; if (idx < 480) s_noise[sn][idx] = pn1; }
    }
    softbar();
  }
}

// ---------------- P2: prior head, fully parallel over all (t,b) rows --------
__global__ __launch_bounds__(512, 2) void prior_kernel(
    const float* __restrict__ deter, const float* __restrict__ noise_prior,
    const float* __restrict__ bp1, const float* __restrict__ bp2,
    const u16* __restrict__ ws, float* __restrict__ out) {
  float* o_pm  = out;
  float* o_ps  = out + TBN*30;
  float* o_pst = out + TBN*60;

  __shared__ __align__(16) u16 s_h1[8][16][232];
  __shared__ float s_pm[8][16][30];
  __shared__ float s_ps[8][16][30];

  const int tid = threadIdx.x;
  const int w = tid >> 6, l = tid & 63;
  const int lr = l & 15, lk = (l >> 4) << 3, crw = (l >> 4) << 2;
  const size_t row0 = (size_t)blockIdx.x*128 + w*16;
  const f32x4 fzero = {0.f, 0.f, 0.f, 0.f};

  for (int idx = tid; idx < 8*16*232/2; idx += 512) ((u32*)&s_h1[0][0][0])[idx] = 0;
  __syncthreads();

  short8 adf[7];
  const float* drow = deter + (row0 + lr)*200;
  #pragma unroll
  for (int ks = 0; ks < 7; ++ks) {
    short8 tf;
    #pragma unroll
    for (int i = 0; i < 8; ++i) {
      int k = ks*32 + lk + i;
      float v = (k < 200) ? __builtin_nontemporal_load(drow + k) : 0.f;
      tf[i] = (short)f2bf(v);
    }
    adf[ks] = tf;
  }
  #pragma unroll
  for (int u = 0; u < 13; ++u) {
    f32x4 acc = fzero;
    #pragma unroll
    for (int ks = 0; ks < 7; ++ks) {
      short8 b = *(const short8*)(ws + OFF_WP1 + ((u*7 + ks) << 9) + l*8);
      acc = mfma16(adf[ks], b, acc);
    }
    int col = u*16 + lr;
    if (col < 200) {
      float bb = bp1[col];
      #pragma unroll
      for (int i = 0; i < 4; ++i)
        s_h1[w][crw + i][col] = f2bf(felu(acc[i] + bb));
    }
  }
  __syncthreads();
  short8 ahf[7];
  #pragma unroll
  for (int ks = 0; ks < 7; ++ks)
    ahf[ks] = *(const short8*)&s_h1[w][lr][ks*32 + lk];
  #pragma unroll
  for (int ct = 0; ct < 4; ++ct) {
    f32x4 acc = fzero;
    #pragma unroll
    for (int ks = 0; ks < 7; ++ks) {
      short8 b = *(const short8*)(ws + OFF_WP2 + ((ct*7 + ks) << 9) + l*8);
      acc = mfma16(ahf[ks], b, acc);
    }
    int col = ct*16 + lr;
    if (col < 60) {
      float bb = bp2[col];
      #pragma unroll
      for (int i = 0; i < 4; ++i) {
        int r = crw + i;
        float v = acc[i] + bb;
        size_t go = (row0 + r)*30;
        if (col < 30) {
          s_pm[w][r][col] = v;
          __builtin_nontemporal_store(v, &o_pm[go + col]);
        } else {
          int c = col - 30;
          float s = fsoftplus(v) + 0.1f;
          s_ps[w][r][c] = s;
          __builtin_nontemporal_store(s, &o_ps[go + c]);
        }
      }
    }
  }
  __syncthreads();
  for (int idx = tid; idx < 3840; idx += 512) {
    int w2 = idx/480, rem = idx - w2*480;
    int r = rem/30, c = rem - r*30;
    size_t grow = (size_t)blockIdx.x*128 + w2*16 + r;
    float pst = s_pm[w2][r][c] + s_ps[w2][r][c]*__builtin_nontemporal_load(noise_prior + grow*30 + c);
    __builtin_nontemporal_store(pst, &o_pst[grow*30 + c]);
  }
}

extern "C" void kernel_launch(void* const* d_in, const int* in_sizes, int n_in,
                              void* d_out, int out_size, void* d_ws, size_t ws_size,
                              hipStream_t stream) {
  const float* obs  = (const float*)d_in[1];
  const float* act  = (const float*)d_in[2];
  const float* pst0 = (const float*)d_in[3];
  const float* pdt0 = (const float*)d_in[4];
  const float* npr  = (const float*)d_in[5];
  const float* npo  = (const float*)d_in[6];
  const float* Wri  = (const float*)d_in[7];
  const float* bri  = (const float*)d_in[8];
  const float* Wih  = (const float*)d_in[9];
  const float* bih  = (const float*)d_in[10];
  const float* Whh  = (const float*)d_in[11];
  const float* bhh  = (const float*)d_in[12];
  const float* Wp1  = (const float*)d_in[13];
  const float* bp1  = (const float*)d_in[14];
  const float* Wp2  = (const float*)d_in[15];
  const float* bp2  = (const float*)d_in[16];
  const float* Wq1  = (const float*)d_in[17];
  const float* bq1  = (const float*)d_in[18];
  const float* Wq2  = (const float*)d_in[19];
  const float* bq2  = (const float*)d_in[20];
  float* out = (float*)d_out;
  u16* ws = (u16*)d_ws;

  prep_frags<<<FRAG_TOTAL/512, 512, 0, stream>>>(Wih, Whh, Wp1, Wq1, Wp2, Wq2, Wri, ws);
  embq_kernel<<<512, 512, 0, stream>>>(obs, bq1, ws, (u16*)(out + TBN*380));
  rollout_kernel<<<64, 512, 0, stream>>>(act, pst0, pdt0, npo, bri,
                                         bih, bhh, bq2, ws, out);
  prior_kernel<<<512, 512, 0, stream>>>(out + TBN*90, npr, bp1, bp2, ws, out);
}

// Round 14
// 758.873 us; speedup vs baseline: 1.0459x; 1.0459x over previous
//
#include <hip/hip_runtime.h>
#include <hip/hip_bf16.h>

typedef unsigned short u16;
typedef unsigned int u32;
typedef __attribute__((ext_vector_type(4))) float f32x4;
typedef __attribute__((ext_vector_type(8))) short short8;
typedef __attribute__((ext_vector_type(8))) __bf16 bf16x8;

#define TBN ((size_t)65536)  // T*B

// frag-layout offsets in u16 elements inside d_ws
#define OFF_WIH  0         // [3 g][13 ct][7 ks][512]; gate stride 46592
#define OFF_WHH  139776
#define OFF_WP1  279552    // [13][7][512]
#define OFF_WQ1D 326144
#define OFF_WP2  372736    // [4][7][512]
#define OFF_WQ2  387072    // PAIRED packing: tile ct, fc<8 -> qm col ct*8+fc; fc>=8 -> qs col ct*8+fc-8
#define OFF_WQ1E 401408    // [32 ks][13 ct][512]
#define OFF_WRIF 614400    // [13 ct][2 ks][512]
#define FRAG_TOTAL 627712  // = 512*1226
#define GSTR 46592

__device__ __forceinline__ u16 f2bf(float f) {
  unsigned u = __builtin_bit_cast(unsigned, f);
  unsigned r = u + 0x7fffu + ((u >> 16) & 1u);
  return (u16)(r >> 16);
}
__device__ __forceinline__ float bf2f(u16 v) {
  unsigned u = ((unsigned)v) << 16;
  return __builtin_bit_cast(float, u);
}
__device__ __forceinline__ float fsig(float x) {
  return __builtin_amdgcn_rcpf(1.f + __expf(-x));
}
__device__ __forceinline__ float ftanh(float x) {
  return 1.f - 2.f * __builtin_amdgcn_rcpf(__expf(2.f * x) + 1.f);
}
__device__ __forceinline__ float fsoftplus(float x) {
  return (x > 20.f) ? x : __logf(1.f + __expf(x));
}
__device__ __forceinline__ float felu(float x) {
  return (x > 0.f) ? x : (__expf(x) - 1.f);
}
__device__ __forceinline__ f32x4 mfma16(short8 a, short8 b, f32x4 c) {
  return __builtin_amdgcn_mfma_f32_16x16x32_bf16(
      __builtin_bit_cast(bf16x8, a), __builtin_bit_cast(bf16x8, b), c, 0, 0, 0);
}
// barrier that does NOT drain vmcnt: LDS-safe, lets global loads/stores fly
__device__ __forceinline__ void softbar() {
  asm volatile("s_waitcnt lgkmcnt(0)\n\ts_barrier" ::: "memory");
}

// ---------------- P0: pack weights into MFMA B-fragment order (bf16) --------
__global__ __launch_bounds__(512) void prep_frags(
    const float* __restrict__ Wih, const float* __restrict__ Whh,
    const float* __restrict__ Wp1, const float* __restrict__ Wq1,
    const float* __restrict__ Wp2, const float* __restrict__ Wq2,
    const float* __restrict__ Wri, u16* __restrict__ ws) {
  int id = blockIdx.x * 512 + threadIdx.x;
  float v = 0.f;
  if (id < 279552) {                       // WIH / WHH  (K=200, N=3x200)
    const float* W = (id < 139776) ? Wih : Whh;
    int idx2 = (id < 139776) ? id : id - 139776;
    int fb = idx2 >> 9, r = idx2 & 511, l = r >> 3, i = r & 7;
    int g = fb / 91, rem = fb % 91, ct = rem / 7, ks = rem % 7;
    int k = ks*32 + ((l >> 4) << 3) + i;
    int col = ct*16 + (l & 15);
    if (k < 200 && col < 200) v = W[k*600 + g*200 + col];
  } else if (id < 372736) {                // WP1 / WQ1D  (K=200, N=200)
    const float* W = (id < 326144) ? Wp1 : Wq1;
    int idx2 = (id < 326144) ? id - 279552 : id - 326144;
    int fb = idx2 >> 9, r = idx2 & 511, l = r >> 3, i = r & 7;
    int ct = fb / 7, ks = fb % 7;
    int k = ks*32 + ((l >> 4) << 3) + i;
    int col = ct*16 + (l & 15);
    if (k < 200 && col < 200) v = W[k*200 + col];
  } else if (id < 387072) {                // WP2  (K=200, N=60)
    int idx2 = id - 372736;
    int fb = idx2 >> 9, r = idx2 & 511, l = r >> 3, i = r & 7;
    int ct = fb / 7, ks = fb % 7;
    int k = ks*32 + ((l >> 4) << 3) + i;
    int col = ct*16 + (l & 15);
    if (k < 200 && col < 60) v = Wp2[k*60 + col];
  } else if (id < 401408) {                // WQ2 (PAIRED qm/qs packing)
    int idx2 = id - 387072;
    int fb = idx2 >> 9, r = idx2 & 511, l = r >> 3, i = r & 7;
    int ct = fb / 7, ks = fb % 7;
    int k = ks*32 + ((l >> 4) << 3) + i;
    int fc = l & 15;
    int qcol = ct*8 + (fc & 7);
    int col = (fc < 8) ? qcol : (30 + qcol);   // fc<8: qm col; fc>=8: qs col
    if (k < 200 && qcol < 30) v = Wq2[k*60 + col];
  } else if (id < 614400) {                // WQ1E (emb rows of Wq1, K=1024)
    int idx2 = id - 401408;
    int fb = idx2 >> 9, r = idx2 & 511, l = r >> 3, i = r & 7;
    int ks = fb / 13, ct = fb % 13;
    int k = ks*32 + ((l >> 4) << 3) + i;
    int col = ct*16 + (l & 15);
    if (col < 200) v = Wq1[(size_t)(200 + k)*200 + col];
  } else {                                 // WRIF (K=36 pad 64, N=200)
    int idx2 = id - 614400;
    int fb = idx2 >> 9, r = idx2 & 511, l = r >> 3, i = r & 7;
    int ct = fb >> 1, ks = fb & 1;
    int k = ks*32 + ((l >> 4) << 3) + i;
    int col = ct*16 + (l & 15);
    if (k < 36 && col < 200) v = Wri[k*200 + col];
  }
  ws[id] = f2bf(v);
}

// ---------------- P1: embq (bf16) = obs_embed @ Wq1[200:,:] + bq1 -----------
__global__ __launch_bounds__(512) void embq_kernel(
    const float* __restrict__ obs, const float* __restrict__ bq1,
    const u16* __restrict__ ws, u16* __restrict__ embq) {
  __shared__ __align__(16) u16 Bl[6656];   // 13 frag-blocks x 1KB
  const int tid = threadIdx.x;
  const int w = tid >> 6, l = tid & 63;
  const int lr = l & 15, lk = (l >> 4) << 3, crw = (l >> 4) << 2;
  const size_t mb = (size_t)blockIdx.x * 128;
  const float* ap = obs + (mb + (size_t)w*16 + lr) * 1024 + lk;
  const u16* wsrc = ws + OFF_WQ1E;
  f32x4 zero = {0.f, 0.f, 0.f, 0.f};
  f32x4 acc[13];
  #pragma unroll
  for (int c = 0; c < 13; ++c) acc[c] = zero;
  for (int ks = 0; ks < 32; ++ks) {
    f32x4 a0 = __builtin_nontemporal_load((const f32x4*)(ap));
    f32x4 a1 = __builtin_nontemporal_load((const f32x4*)(ap + 4));
    ap += 32;
    __syncthreads();
    {
      const u16* src = wsrc + (size_t)ks * 6656;
      *(short8*)(Bl + tid*8) = *(const short8*)(src + tid*8);
      int idx = 512 + tid;
      if (idx < 832)
        *(short8*)(Bl + idx*8) = *(const short8*)(src + idx*8);
    }
    __syncthreads();
    short8 af;
    af[0]=(short)f2bf(a0[0]); af[1]=(short)f2bf(a0[1]); af[2]=(short)f2bf(a0[2]); af[3]=(short)f2bf(a0[3]);
    af[4]=(short)f2bf(a1[0]); af[5]=(short)f2bf(a1[1]); af[6]=(short)f2bf(a1[2]); af[7]=(short)f2bf(a1[3]);
    #pragma unroll
    for (int c = 0; c < 13; ++c) {
      short8 bf = *(const short8*)(Bl + c*512 + l*8);
      acc[c] = mfma16(af, bf, acc[c]);
    }
  }
  #pragma unroll
  for (int c = 0; c < 13; ++c) {
    int col = c*16 + lr;
    if (col < 200) {
      float bias = bq1[col];
      #pragma unroll
      for (int i = 0; i < 4; ++i) {
        size_t row = mb + (size_t)w*16 + crw + i;
        __builtin_nontemporal_store(f2bf(acc[c][i] + bias), &embq[row*400 + col]);
      }
    }
  }
}

// ---------------- R: the 64-step rollout, 64 blocks x 16 batch rows ---------
__global__ __launch_bounds__(512, 1) void rollout_kernel(
    const float* __restrict__ action, const float* __restrict__ prev_stoch,
    const float* __restrict__ prev_deter, const float* __restrict__ noise_post,
    const float* __restrict__ bri, const float* __restrict__ bih,
    const float* __restrict__ bhh, const float* __restrict__ bq2,
    const u16* __restrict__ ws, float* __restrict__ out) {
  float* o_d1  = out + TBN*90;
  float* o_qm  = out + TBN*290;
  float* o_qs  = out + TBN*320;
  float* o_qst = out + TBN*350;
  float* o_d2  = out + TBN*380;          // rows hold embq(t) bf16 until consumed
  const u32* embq32 = (const u32*)o_d2;

  __shared__ __align__(16) u16 s_wqd[46592];          // Wq1d frags, LDS-resident
  __shared__ float s_bih[600], s_bhh[600], s_bri[200], s_bq2[60];
  __shared__ float s_deter[16][200];
  __shared__ __align__(16) u16 s_dbf2[2][16][232];
  __shared__ __align__(16) u16 s_abf[16][64];
  __shared__ __align__(16) u16 s_xbf[16][232];
  __shared__ __align__(16) u16 s_h2[16][232];
  __shared__ __align__(4)  u16 s_embq[3200];          // single buffer
  __shared__ float s_noise[2][480];
  __shared__ float s_qml[16][30], s_qsl[16][30];

  const int tid = threadIdx.x;
  const int w = tid >> 6, l = tid & 63;
  const int lr = l & 15, lk = (l >> 4) << 3, crw = (l >> 4) << 2;
  const int rb = blockIdx.x * 16;
  const f32x4 fzero = {0.f, 0.f, 0.f, 0.f};
  const int uA0 = w;
  const int uA1 = (w < 5) ? (8 + w) : 12;
  const bool validR1 = (w < 5);

  // ---- zero-init ----
  for (int idx = tid; idx < 16*232; idx += 512) {
    (&s_xbf[0][0])[idx] = 0; (&s_h2[0][0])[idx] = 0;
    (&s_dbf2[0][0][0])[idx] = 0; (&s_dbf2[1][0][0])[idx] = 0;
  }
  for (int idx = tid; idx < 16*64; idx += 512) (&s_abf[0][0])[idx] = 0;
  __syncthreads();

  for (int idx = tid; idx < 600; idx += 512) { s_bih[idx] = bih[idx]; s_bhh[idx] = bhh[idx]; }
  if (tid < 200) s_bri[tid] = bri[tid];
  if (tid < 60)  s_bq2[tid] = bq2[tid];
  // Wq1d -> LDS (once)
  for (int i = tid; i < 5824; i += 512)
    ((short8*)s_wqd)[i] = ((const short8*)(ws + OFF_WQ1D))[i];
  for (int idx = tid; idx < 3200; idx += 512) {
    int r = idx/200, c = idx - r*200;
    float d = prev_deter[(rb + r)*200 + c];
    s_deter[r][c] = d;
    s_dbf2[0][r][c] = f2bf(d);
  }
  if (tid < 480) { int r = tid/30, c = tid - r*30;
    s_abf[r][6 + c] = f2bf(prev_stoch[(rb + r)*30 + c]); }
  if (tid < 96) { s_abf[tid/6][tid - (tid/6)*6] = f2bf(action[(size_t)rb*6 + tid]); }
  {
    const u32* esrc = embq32 + (size_t)rb * 200;
    u32* ed = (u32*)s_embq;
    #pragma unroll
    for (int q = 0; q < 4; ++q) {
      int idx = q*512 + tid;
      if (idx < 1600) { int r = idx/100, c = idx - r*100; ed[idx] = esrc[r*200 + c]; }
    }
  }
  if (tid < 480) s_noise[0][tid] = noise_post[(size_t)rb*30 + tid];

  // resident fragments
  short8 wri0[2], wri1[2], wq2f[7];
  #pragma unroll
  for (int ks = 0; ks < 2; ++ks) {
    wri0[ks] = *(const short8*)(ws + OFF_WRIF + ((uA0*2 + ks) << 9) + l*8);
    wri1[ks] = *(const short8*)(ws + OFF_WRIF + ((uA1*2 + ks) << 9) + l*8);
  }
  #pragma unroll
  for (int ks = 0; ks < 7; ++ks)
    wq2f[ks] = *(const short8*)(ws + OFF_WQ2 + (((w & 3)*7 + ks) << 9) + l*8);
  __syncthreads();

  for (int t = 0; t < 64; ++t) {
    const size_t brow = (size_t)t*1024 + rb;
    const int sc = t & 1, sn = sc ^ 1;   // parity for noise AND s_dbf2

    // ---- A': x = elu([act|stoch]@Wri + bri) via MFMA ----
    {
      short8 a0 = *(const short8*)&s_abf[lr][lk];
      short8 a1 = *(const short8*)&s_abf[lr][32 + lk];
      f32x4 acc = mfma16(a1, wri0[1], mfma16(a0, wri0[0], fzero));
      int col = uA0*16 + lr;                    // < 128
      #pragma unroll
      for (int i = 0; i < 4; ++i)
        s_xbf[crw + i][col] = f2bf(felu(acc[i] + s_bri[col]));
      if (validR1) {
        f32x4 acc2 = mfma16(a1, wri1[1], mfma16(a0, wri1[0], fzero));
        int col2 = uA1*16 + lr;
        if (col2 < 200) {
          #pragma unroll
          for (int i = 0; i < 4; ++i)
            s_xbf[crw + i][col2] = f2bf(felu(acc2[i] + s_bri[col2]));
        }
      }
    }
    softbar();

    // ---- B'+C: gates GEMM (all 3 gates per unit) + in-register GRU combine ----
    #pragma unroll
    for (int jr = 0; jr < 2; ++jr) {
      const int u = jr ? uA1 : uA0;
      const bool valid = jr ? validR1 : true;
      if (valid) {
        const u32 base = (u32)(((u*7) << 9) + l*8);
        short8 g0i[7], g0h[7], g1i[7], g1h[7], g2i[7], g2h[7];
        #pragma unroll
        for (int ks = 0; ks < 7; ++ks) {
          g0i[ks] = *(const short8*)(ws + OFF_WIH + base + ks*512);
          g0h[ks] = *(const short8*)(ws + OFF_WHH + base + ks*512);
        }
        #pragma unroll
        for (int ks = 0; ks < 7; ++ks) {
          g1i[ks] = *(const short8*)(ws + OFF_WIH + GSTR + base + ks*512);
          g1h[ks] = *(const short8*)(ws + OFF_WHH + GSTR + base + ks*512);
        }
        f32x4 aR = fzero;
        #pragma unroll
        for (int ks = 0; ks < 7; ++ks) {
          short8 ax = *(const short8*)&s_xbf[lr][ks*32 + lk];
          short8 ad = *(const short8*)&s_dbf2[sc][lr][ks*32 + lk];
          aR = mfma16(ad, g0h[ks], mfma16(ax, g0i[ks], aR));
        }
        #pragma unroll
        for (int ks = 0; ks < 7; ++ks) {
          g2i[ks] = *(const short8*)(ws + OFF_WIH + 2*GSTR + base + ks*512);
          g2h[ks] = *(const short8*)(ws + OFF_WHH + 2*GSTR + base + ks*512);
        }
        f32x4 aZ = fzero;
        #pragma unroll
        for (int ks = 0; ks < 7; ++ks) {
          short8 ax = *(const short8*)&s_xbf[lr][ks*32 + lk];
          short8 ad = *(const short8*)&s_dbf2[sc][lr][ks*32 + lk];
          aZ = mfma16(ad, g1h[ks], mfma16(ax, g1i[ks], aZ));
        }
        f32x4 aN = fzero, aH = fzero;
        #pragma unroll
        for (int ks = 0; ks < 7; ++ks) {
          short8 ax = *(const short8*)&s_xbf[lr][ks*32 + lk];
          short8 ad = *(const short8*)&s_dbf2[sc][lr][ks*32 + lk];
          aN = mfma16(ax, g2i[ks], aN);
          aH = mfma16(ad, g2h[ks], aH);
        }
        int col = u*16 + lr;
        if (col < 200) {
          float bR = s_bih[col]       + s_bhh[col];
          float bZ = s_bih[200 + col] + s_bhh[200 + col];
          float bN = s_bih[400 + col];
          float bH = s_bhh[400 + col];
          #pragma unroll
          for (int i = 0; i < 4; ++i) {
            int row = crw + i;
            float rg = fsig(aR[i] + bR);
            float zg = fsig(aZ[i] + bZ);
            float ng = ftanh(aN[i] + bN + rg*(aH[i] + bH));
            float dn = (1.f - zg)*ng + zg*s_deter[row][col];
            s_deter[row][col] = dn;
            s_dbf2[sn][row][col] = f2bf(dn);
          }
        }
      }
    }
    // stream prefetch for t+1 (issued AFTER all frag loads; consumed in E2)
    u32 pe0 = 0, pe1 = 0, pe2 = 0, pe3 = 0; float pact = 0.f, pnoise = 0.f;
    {
      const int t2 = (t < 63) ? (t + 1) : 63;
      const size_t brow2 = (size_t)t2*1024 + rb;
      const u32* esrc = embq32 + brow2*200;
      { int idx = tid;        int r = idx/100, c = idx - r*100; pe0 = esrc[r*200 + c]; }
      { int idx = tid + 512;  int r = idx/100, c = idx - r*100; pe1 = esrc[r*200 + c]; }
      { int idx = tid + 1024; int r = idx/100, c = idx - r*100; pe2 = esrc[r*200 + c]; }
      if (tid < 64) { int idx = tid + 1536; int r = idx/100, c = idx - r*100; pe3 = esrc[r*200 + c]; }
      if (tid < 96)  pact = action[brow2*6 + tid];
      if (tid < 480) pnoise = noise_post[brow2*30 + tid];
    }
    softbar();   // deter ready; streams in flight

    // ---- D: h2 = elu(deter_new@Wq1d + embq), Wq1d from LDS ----
    {
      f32x4 acc = fzero;
      #pragma unroll
      for (int ks = 0; ks < 7; ++ks) {
        short8 ad = *(const short8*)&s_dbf2[sn][lr][ks*32 + lk];
        short8 bw = *(const short8*)&s_wqd[((uA0*7 + ks) << 9) + l*8];
        acc = mfma16(ad, bw, acc);
      }
      {
        int col = uA0*16 + lr;                  // < 128
        #pragma unroll
        for (int i = 0; i < 4; ++i) {
          int row = crw + i;
          float v = acc[i] + bf2f(s_embq[row*200 + col]);
          s_h2[row][col] = f2bf(felu(v));
        }
      }
      if (validR1) {
        f32x4 acc2 = fzero;
        #pragma unroll
        for (int ks = 0; ks < 7; ++ks) {
          short8 ad = *(const short8*)&s_dbf2[sn][lr][ks*32 + lk];
          short8 bw = *(const short8*)&s_wqd[((uA1*7 + ks) << 9) + l*8];
          acc2 = mfma16(ad, bw, acc2);
        }
        int col2 = uA1*16 + lr;
        if (col2 < 200) {
          #pragma unroll
          for (int i = 0; i < 4; ++i) {
            int row = crw + i;
            float v = acc2[i] + bf2f(s_embq[row*200 + col2]);
            s_h2[row][col2] = f2bf(felu(v));
          }
        }
      }
    }
    softbar();   // h2 ready; embq consumed

    // ---- E1: posterior head (waves 0-3); o_d1+o_d2 (waves 4-7) ----
    if (w < 4) {
      f32x4 acc = fzero;
      #pragma unroll
      for (int ks = 0; ks < 7; ++ks) {
        short8 a = *(const short8*)&s_h2[lr][ks*32 + lk];
        acc = mfma16(a, wq2f[ks], acc);
      }
      const int qcol = w*8 + (lr & 7);
      const bool isQm = (lr < 8);
      if (qcol < 30) {
        const float bias = isQm ? s_bq2[qcol] : s_bq2[30 + qcol];
        #pragma unroll
        for (int i = 0; i < 4; ++i) {
          int row = crw + i;
          float v = acc[i] + bias;
          size_t go = (brow + row)*30 + qcol;
          if (isQm) {
            s_qml[row][qcol] = v;
            __builtin_nontemporal_store(v, &o_qm[go]);
          } else {
            float s = fsoftplus(v) + 0.1f;
            s_qsl[row][qcol] = s;
            __builtin_nontemporal_store(s, &o_qs[go]);
          }
        }
      }
    } else {
      for (int idx = tid - 256; idx < 3200; idx += 256) {
        int r = idx/200, j = idx - r*200;
        float dv = s_deter[r][j];
        __builtin_nontemporal_store(dv, &o_d1[(brow + r)*200 + j]);
        __builtin_nontemporal_store(dv, &o_d2[(brow + r)*200 + j]);
      }
    }
    softbar();

    // ---- E2: posterior sample; stage t+1 streams (embq/act/noise) + abf ----
    if (tid < 480) {
      int r = tid/30, c = tid - r*30;
      float qst = s_qml[r][c] + s_qsl[r][c]*s_noise[sc][tid];
      __builtin_nontemporal_store(qst, &o_qst[(brow + r)*30 + c]);
      s_abf[r][6 + c] = f2bf(qst);
    }
    if (tid < 96) { s_abf[tid/6][tid - (tid/6)*6] = f2bf(pact); }
    {
      u32* ed = (u32*)s_embq;
      ed[tid] = pe0;
      ed[512 + tid] = pe1;
      ed[1024 + tid] = pe2;
      if (tid < 64) ed[1536 + tid] = pe3;
    }
    if (tid < 480) s_noise[sn][tid] = pnoise;
    softbar();
  }
}

// ---------------- P2: prior head, fully parallel over all (t,b) rows --------
__global__ __launch_bounds__(512, 2) void prior_kernel(
    const float* __restrict__ deter, const float* __restrict__ noise_prior,
    const float* __restrict__ bp1, const float* __restrict__ bp2,
    const u16* __restrict__ ws, float* __restrict__ out) {
  float* o_pm  = out;
  float* o_ps  = out + TBN*30;
  float* o_pst = out + TBN*60;

  __shared__ __align__(16) u16 s_h1[8][16][232];
  __shared__ float s_pm[8][16][30];
  __shared__ float s_ps[8][16][30];

  const int tid = threadIdx.x;
  const int w = tid >> 6, l = tid & 63;
  const int lr = l & 15, lk = (l >> 4) << 3, crw = (l >> 4) << 2;
  const size_t row0 = (size_t)blockIdx.x*128 + w*16;
  const f32x4 fzero = {0.f, 0.f, 0.f, 0.f};

  for (int idx = tid; idx < 8*16*232/2; idx += 512) ((u32*)&s_h1[0][0][0])[idx] = 0;
  __syncthreads();

  short8 adf[7];
  const float* drow = deter + (row0 + lr)*200;
  #pragma unroll
  for (int ks = 0; ks < 7; ++ks) {
    short8 tf;
    #pragma unroll
    for (int i = 0; i < 8; ++i) {
      int k = ks*32 + lk + i;
      float v = (k < 200) ? __builtin_nontemporal_load(drow + k) : 0.f;
      tf[i] = (short)f2bf(v);
    }
    adf[ks] = tf;
  }
  #pragma unroll
  for (int u = 0; u < 13; ++u) {
    f32x4 acc = fzero;
    #pragma unroll
    for (int ks = 0; ks < 7; ++ks) {
      short8 b = *(const short8*)(ws + OFF_WP1 + ((u*7 + ks) << 9) + l*8);
      acc = mfma16(adf[ks], b, acc);
    }
    int col = u*16 + lr;
    if (col < 200) {
      float bb = bp1[col];
      #pragma unroll
      for (int i = 0; i < 4; ++i)
        s_h1[w][crw + i][col] = f2bf(felu(acc[i] + bb));
    }
  }
  __syncthreads();
  short8 ahf[7];
  #pragma unroll
  for (int ks = 0; ks < 7; ++ks)
    ahf[ks] = *(const short8*)&s_h1[w][lr][ks*32 + lk];
  #pragma unroll
  for (int ct = 0; ct < 4; ++ct) {
    f32x4 acc = fzero;
    #pragma unroll
    for (int ks = 0; ks < 7; ++ks) {
      short8 b = *(const short8*)(ws + OFF_WP2 + ((ct*7 + ks) << 9) + l*8);
      acc = mfma16(ahf[ks], b, acc);
    }
    int col = ct*16 + lr;
    if (col < 60) {
      float bb = bp2[col];
      #pragma unroll
      for (int i = 0; i < 4; ++i) {
        int r = crw + i;
        float v = acc[i] + bb;
        size_t go = (row0 + r)*30;
        if (col < 30) {
          s_pm[w][r][col] = v;
          __builtin_nontemporal_store(v, &o_pm[go + col]);
        } else {
          int c = col - 30;
          float s = fsoftplus(v) + 0.1f;
          s_ps[w][r][c] = s;
          __builtin_nontemporal_store(s, &o_ps[go + c]);
        }
      }
    }
  }
  __syncthreads();
  for (int idx = tid; idx < 3840; idx += 512) {
    int w2 = idx/480, rem = idx - w2*480;
    int r = rem/30, c = rem - r*30;
    size_t grow = (size_t)blockIdx.x*128 + w2*16 + r;
    float pst = s_pm[w2][r][c] + s_ps[w2][r][c]*__builtin_nontemporal_load(noise_prior + grow*30 + c);
    __builtin_nontemporal_store(pst, &o_pst[grow*30 + c]);
  }
}

extern "C" void kernel_launch(void* const* d_in, const int* in_sizes, int n_in,
                              void* d_out, int out_size, void* d_ws, size_t ws_size,
                              hipStream_t stream) {
  const float* obs  = (const float*)d_in[1];
  const float* act  = (const float*)d_in[2];
  const float* pst0 = (const float*)d_in[3];
  const float* pdt0 = (const float*)d_in[4];
  const float* npr  = (const float*)d_in[5];
  const float* npo  = (const float*)d_in[6];
  const float* Wri  = (const float*)d_in[7];
  const float* bri  = (const float*)d_in[8];
  const float* Wih  = (const float*)d_in[9];
  const float* bih  = (const float*)d_in[10];
  const float* Whh  = (const float*)d_in[11];
  const float* bhh  = (const float*)d_in[12];
  const float* Wp1  = (const float*)d_in[13];
  const float* bp1  = (const float*)d_in[14];
  const float* Wp2  = (const float*)d_in[15];
  const float* bp2  = (const float*)d_in[16];
  const float* Wq1  = (const float*)d_in[17];
  const float* bq1  = (const float*)d_in[18];
  const float* Wq2  = (const float*)d_in[19];
  const float* bq2  = (const float*)d_in[20];
  float* out = (float*)d_out;
  u16* ws = (u16*)d_ws;

  prep_frags<<<FRAG_TOTAL/512, 512, 0, stream>>>(Wih, Whh, Wp1, Wq1, Wp2, Wq2, Wri, ws);
  embq_kernel<<<512, 512, 0, stream>>>(obs, bq1, ws, (u16*)(out + TBN*380));
  rollout_kernel<<<64, 512, 0, stream>>>(act, pst0, pdt0, npo, bri,
                                         bih, bhh, bq2, ws, out);
  prior_kernel<<<512, 512, 0, stream>>>(out + TBN*90, npr, bp1, bp2, ws, out);
}